// Round 6
// baseline (109.390 us; speedup 1.0000x reference)
//
#include <hip/hip_runtime.h>
#include <hip/hip_bf16.h>

// E3nnSimpleEdgeBlock via bf16 MFMA + block-shared LDS B-staging (2-phase pipeline).
//   out0[e,w]   = C0*( sum_uv W000[u,v,w] a0[u]b0[v] + IS3 * sum_uv W110[u,v,w] dot(a1[u],b1[v]) )
//   out1[e,w,k] = C1*( IS3*( sum W011 a0[u]b1[v,k] + sum W101 a1[u,k]b0[v] ) + IS6*sum W111 cross_k )
// 4 waves/block = 4 edge-tiles of 16, ALL waves iterate the same v: the 10KB/v
// B-fragment slice is staged once per block into LDS (global_load_lds, dbuf),
// prefetched one v ahead; the per-iter __syncthreads() vmcnt-drain is the
// pipeline barrier (2-phase T3-minimum recipe).
//
// mfma_f32_16x16x32_bf16 lane mapping (m89-verified):
//   A[row=l&15][k=8*(l>>4)+j]  B[k=8*(l>>4)+j][col=l&15]  D[row=4*(l>>4)+r][col=l&15]

typedef __attribute__((ext_vector_type(8))) short short8;        // 8 bf16
typedef __attribute__((ext_vector_type(4))) float f32x4;
typedef __attribute__((ext_vector_type(4))) unsigned short u16x4;

#define AS_GLOBAL __attribute__((address_space(1)))
#define AS_LOCAL  __attribute__((address_space(3)))

static constexpr float C_OUT0    = 0.022097086912079608f; // 1/sqrt(2048)
static constexpr float C_OUT1    = 0.03125f;              // 1/sqrt(1024)
static constexpr float INV_SQRT3 = 0.57735026918962576f;
static constexpr float INV_SQRT6 = 0.40824829046386302f;

static __device__ __forceinline__ short bfbits(float x) {
    __hip_bfloat16 h = __float2bfloat16(x);
    return __builtin_bit_cast(short, h);
}
static __device__ __forceinline__ float b2f(unsigned short u) {
    unsigned int x = ((unsigned int)u) << 16;
    return __builtin_bit_cast(float, x);
}
static __device__ __forceinline__ void gload_lds16(const void* g, void* l) {
    __builtin_amdgcn_global_load_lds((const AS_GLOBAL unsigned int*)g,
                                     (AS_LOCAL unsigned int*)l, 16, 0, 0);
}

// ---------------------------------------------------------------------------
// prep (unchanged, post-timing-proven): bf16 B-fragment stream in d_ws.
// Layout: for v, frag f (0..9), lane l: 8 bf16 = 16 B. Slice per v = 10240 B.
//   f = 2g + nf;  g: 0=W000 1=W110 2=W011 3=W101 4=W111;  w = nf*16 + (l&15)
//   element j: scale_g * Wg[(8*(l>>4)+j)*1024 + v*32 + w].  Total 327680 B.
// ---------------------------------------------------------------------------
__global__ __launch_bounds__(256) void prep_weights(
    const float* __restrict__ W000, const float* __restrict__ W110,
    const float* __restrict__ W011, const float* __restrict__ W101,
    const float* __restrict__ W111, short* __restrict__ wsB)
{
    const int t = blockIdx.x * 256 + threadIdx.x;   // 0 .. 5*32768-1
    if (t >= 5 * 32768) return;
    const int g   = t >> 15;
    const int idx = t & 32767;          // u*1024 + v*32 + w
    const int u = idx >> 10, v = (idx >> 5) & 31, w = idx & 31;
    const float* Wp = (g == 0) ? W000 : (g == 1) ? W110 : (g == 2) ? W011
                    : (g == 3) ? W101 : W111;
    const float s = (g == 0) ? C_OUT0
                  : (g == 1) ? C_OUT0 * INV_SQRT3
                  : (g == 4) ? C_OUT1 * INV_SQRT6
                  :            C_OUT1 * INV_SQRT3;
    const int f = 2 * g + (w >> 4);
    const int l = ((u >> 3) << 4) | (w & 15);
    const int j = u & 7;
    wsB[(((v * 10 + f) * 64) + l) * 8 + j] = bfbits(s * Wp[idx]);
}

// ---------------------------------------------------------------------------
// main: 256 threads = 4 waves = 4 edge-tiles (16 edges each), same-v lockstep.
// LDS 36864 B: phase1 x1 stage [64][33 float4] (33792 B, then dead) overlaps
// { bs: bf16 [32 v][64 e][4 comp] = 16384 B | ldsB: 2 x 10240 B dbuf }.
// ---------------------------------------------------------------------------
__global__ __launch_bounds__(256, 4) void e3nn_stage(
    const float* __restrict__ x1, const float* __restrict__ x2,
    const short8* __restrict__ wsB, float* __restrict__ out, int E)
{
    __shared__ __align__(16) char smem[36864];
    float4*         x1s = (float4*)smem;            // phase 1 only
    unsigned short* bsu = (unsigned short*)smem;    // bytes [0, 16384)
    char*          ldsB = smem + 16384;             // bytes [16384, 36864)

    const int tid   = threadIdx.x;
    const int l     = tid & 63;
    const int wv    = tid >> 6;
    const int eBase = blockIdx.x * 64;

    // ---- phase 1: stage x1 tile (64 x 32 float4, padded stride 33) ----
    const float4* x1v = (const float4*)x1;
    for (int i = tid; i < 64 * 32; i += 256) {
        const int e = i >> 5, c4 = i & 31;
        float4 val = {0.f, 0.f, 0.f, 0.f};
        if (eBase + e < E) val = x1v[(size_t)(eBase + e) * 32 + c4];
        x1s[e * 33 + c4] = val;
    }
    __syncthreads();

    // ---- hoist per-lane a-values (f32) ----
    const int eloc = l & 15;
    const int u0   = (l >> 4) * 8;
    const float* row = (const float*)(x1s + ((wv * 16 + eloc) * 33));
    float a0r[8], a1r[3][8];
    #pragma unroll
    for (int j = 0; j < 8; ++j) {
        a0r[j] = row[u0 + j];
        #pragma unroll
        for (int c = 0; c < 3; ++c)
            a1r[c][j] = row[32 + 3 * (u0 + j) + c];
    }
    __syncthreads();   // x1s region dead after this

    // ---- phase 2: bs[v][e][comp] (bf16) + prologue stage of B[v=0] ----
    for (int i = tid; i < 64 * 128; i += 256) {
        const int e = i >> 7, r = i & 127;
        float val = 0.f;
        if (eBase + e < E) val = x2[(size_t)(eBase + e) * 128 + r];
        const unsigned short hb = (unsigned short)bfbits(val);
        if (r < 32) {
            bsu[(r * 64 + e) * 4 + 0] = hb;                 // b0 at v=r
        } else {
            const int q = r - 32, vv = q / 3, c = q - 3 * vv;
            bsu[(vv * 64 + e) * 4 + 1 + c] = hb;            // b1c at v=vv
        }
    }
    {   // stage v=0 slice into buffer 0: 640 chunks of 16 B
        const char* g = (const char*)wsB;
        #pragma unroll
        for (int r = 0; r < 3; ++r) {
            const int chunk = r * 256 + wv * 64;            // wave-uniform
            if (chunk < 640)
                gload_lds16(g + (chunk + l) * 16, ldsB + chunk * 16);
        }
    }
    __syncthreads();   // bs visible + stage 0 drained

    // ---- main v loop: prefetch v+1, compute v, one barrier per iter ----
    const f32x4 zero = {0.f, 0.f, 0.f, 0.f};
    f32x4 acc0[2]    = {zero, zero};
    f32x4 acc1[3][2] = {{zero, zero}, {zero, zero}, {zero, zero}};

    const unsigned short* bsrow = bsu + (wv * 16 + eloc) * 4;

    for (int v = 0; v < 32; ++v) {
        const int cur = v & 1;
        // issue next-slice stage (drained by this iter's end barrier)
        if (v + 1 < 32) {
            const char* g  = (const char*)wsB + (v + 1) * 10240;
            char*       lb = ldsB + (cur ^ 1) * 10240;
            #pragma unroll
            for (int r = 0; r < 3; ++r) {
                const int chunk = r * 256 + wv * 64;
                if (chunk < 640)
                    gload_lds16(g + (chunk + l) * 16, lb + chunk * 16);
            }
        }

        // b components for this lane's edge (broadcast across the 4 u-groups)
        const u16x4 bq = *(const u16x4*)(bsrow + v * 256);
        const float b0 = b2f(bq.x), bx = b2f(bq.y), by = b2f(bq.z), bz = b2f(bq.w);
        const float bv[3] = {bx, by, bz};

        const char* bb = ldsB + cur * 10240;
        #define BFRAG(f) (*(const short8*)(bb + (((f) * 64) + l) * 16))

        short8 A;
        // out0 ch0: a0[u]*b0
        #pragma unroll
        for (int j = 0; j < 8; ++j) A[j] = bfbits(a0r[j] * b0);
        acc0[0] = __builtin_amdgcn_mfma_f32_16x16x32_bf16(A, BFRAG(0), acc0[0], 0, 0, 0);
        acc0[1] = __builtin_amdgcn_mfma_f32_16x16x32_bf16(A, BFRAG(1), acc0[1], 0, 0, 0);
        // out0 ch1: dot(a1,b1)
        #pragma unroll
        for (int j = 0; j < 8; ++j)
            A[j] = bfbits(a1r[0][j] * bx + a1r[1][j] * by + a1r[2][j] * bz);
        acc0[0] = __builtin_amdgcn_mfma_f32_16x16x32_bf16(A, BFRAG(2), acc0[0], 0, 0, 0);
        acc0[1] = __builtin_amdgcn_mfma_f32_16x16x32_bf16(A, BFRAG(3), acc0[1], 0, 0, 0);
        // out1 component kx
        #pragma unroll
        for (int kx = 0; kx < 3; ++kx) {
            const int ii = (kx + 1) % 3, jj = (kx + 2) % 3;
            short8 A011, A101, A111;
            #pragma unroll
            for (int j = 0; j < 8; ++j) {
                A011[j] = bfbits(a0r[j] * bv[kx]);
                A101[j] = bfbits(a1r[kx][j] * b0);
                A111[j] = bfbits(a1r[ii][j] * bv[jj] - a1r[jj][j] * bv[ii]);
            }
            acc1[kx][0] = __builtin_amdgcn_mfma_f32_16x16x32_bf16(A011, BFRAG(4), acc1[kx][0], 0, 0, 0);
            acc1[kx][1] = __builtin_amdgcn_mfma_f32_16x16x32_bf16(A011, BFRAG(5), acc1[kx][1], 0, 0, 0);
            acc1[kx][0] = __builtin_amdgcn_mfma_f32_16x16x32_bf16(A101, BFRAG(6), acc1[kx][0], 0, 0, 0);
            acc1[kx][1] = __builtin_amdgcn_mfma_f32_16x16x32_bf16(A101, BFRAG(7), acc1[kx][1], 0, 0, 0);
            acc1[kx][0] = __builtin_amdgcn_mfma_f32_16x16x32_bf16(A111, BFRAG(8), acc1[kx][0], 0, 0, 0);
            acc1[kx][1] = __builtin_amdgcn_mfma_f32_16x16x32_bf16(A111, BFRAG(9), acc1[kx][1], 0, 0, 0);
        }
        #undef BFRAG

        __syncthreads();   // drains stage loads (vmcnt) + guards dbuf reuse
    }

    // ---- epilogue (scales pre-baked into weights) ----
    const int be0 = wv * 16 + (l >> 4) * 4;
    #pragma unroll
    for (int nf = 0; nf < 2; ++nf) {
        const int w = nf * 16 + (l & 15);
        #pragma unroll
        for (int r = 0; r < 4; ++r) {
            const int ge = eBase + be0 + r;
            if (ge < E) {
                const size_t base = (size_t)ge * 128;
                out[base + w]              = acc0[nf][r];
                out[base + 32 + 3 * w + 0] = acc1[0][nf][r];
                out[base + 32 + 3 * w + 1] = acc1[1][nf][r];
                out[base + 32 + 3 * w + 2] = acc1[2][nf][r];
            }
        }
    }
}

extern "C" void kernel_launch(void* const* d_in, const int* in_sizes, int n_in,
                              void* d_out, int out_size, void* d_ws, size_t ws_size,
                              hipStream_t stream) {
    const float* x1   = (const float*)d_in[0];
    const float* x2   = (const float*)d_in[1];
    const float* W000 = (const float*)d_in[2];
    const float* W110 = (const float*)d_in[3];
    const float* W011 = (const float*)d_in[4];
    const float* W101 = (const float*)d_in[5];
    const float* W111 = (const float*)d_in[6];
    float* out = (float*)d_out;

    const int E = in_sizes[0] / 128;

    hipLaunchKernelGGL(prep_weights, dim3((5 * 32768 + 255) / 256), dim3(256), 0, stream,
                       W000, W110, W011, W101, W111, (short*)d_ws);

    const int grid = (E + 63) / 64;
    hipLaunchKernelGGL(e3nn_stage, dim3(grid), dim3(256), 0, stream,
                       x1, x2, (const short8*)d_ws, out, E);
}